// Round 4
// baseline (201.121 us; speedup 1.0000x reference)
//
#include <hip/hip_runtime.h>

// VQ-VAE forward: N=131072 rows (D=64), K=512 codes.
// Outputs flat: [loss(1) | quantized_st(8388608, NCHW) | perplexity(1) | encodings(131072x512)]
//
// R4 theory (from R3 counters: VALUBusy 32%, occ 21.8% = 2 waves/SIMD, VALU-busy time ==
// FMA floor): latency-bound on the per-code s_load chain. Fix = 2x the wave pool:
//  - 1 row/lane + K-split x2 -> 4096 waves = 4 waves/SIMD (R2 geometry, but WITH the R3
//    fixes: readfirstlane-uniform k (s_load path) + asm-pinned x (no global re-fetch)).
//  - __launch_bounds__(256,4) caps VGPR at 128 (need ~100).

#define OFF_Q    1
#define OFF_PERP 8388609
#define OFF_ENC  8388610

__global__ __launch_bounds__(512) void vq_prep(const float* __restrict__ emb,
                                               float* __restrict__ Bk,
                                               unsigned* __restrict__ counts,
                                               unsigned long long* __restrict__ lossAcc) {
    int k = threadIdx.x;  // 512 threads, one per code
    const float4* e4 = reinterpret_cast<const float4*>(emb) + k * 16;
    float s = 0.f;
    #pragma unroll
    for (int i = 0; i < 16; ++i) {
        float4 v = e4[i];
        s += v.x * v.x + v.y * v.y + v.z * v.z + v.w * v.w;
    }
    Bk[k] = s;
    counts[k] = 0u;
    if (k == 0) *lossAcc = 0ull;
}

__global__ __launch_bounds__(256, 4) void vq_main(const float* __restrict__ in,
                                                  const float* __restrict__ emb,
                                                  const float* __restrict__ Bk,
                                                  unsigned* __restrict__ counts,
                                                  unsigned long long* __restrict__ lossAcc,
                                                  float* __restrict__ out) {
    const int tid  = (int)threadIdx.x;
    const int lane = tid & 63;
    const int wv   = tid >> 6;                                        // 0..3
    const int gib  = __builtin_amdgcn_readfirstlane(wv >> 1);         // row-group in block
    const int half = __builtin_amdgcn_readfirstlane(wv & 1);          // K-half (uniform!)
    const int g    = (int)blockIdx.x * 2 + gib;                       // 0..2047 = b*64+h
    const int bb   = g >> 6;
    const int hh   = g & 63;
    const size_t inBase = (size_t)bb * 262144 + (size_t)hh * 64 + (size_t)lane;

    __shared__ float sd[4][64];
    __shared__ int   sk[4][64];

    // Load this lane's row: x[c] = inputs[b, c, h, w]; coalesced across lanes per c.
    float x[64];
    #pragma unroll
    for (int c = 0; c < 64; ++c) x[c] = in[inBase + (size_t)c * 4096];
    // Pin in VGPRs: opaque defs, compiler cannot re-load from global (R1/R2 lesson).
    #pragma unroll
    for (int i = 0; i < 64; ++i) asm volatile("" : "+v"(x[i]));

    // ||x||^2
    float a0 = 0.f, a1 = 0.f, a2 = 0.f, a3 = 0.f;
    #pragma unroll
    for (int c = 0; c < 64; c += 4) {
        a0 += x[c] * x[c];
        a1 += x[c + 1] * x[c + 1];
        a2 += x[c + 2] * x[c + 2];
        a3 += x[c + 3] * x[c + 3];
    }
    const float A = (a0 + a1) + (a2 + a3);

    // Zero-fill this wave's half of the group's encodings slab: 16384 floats,
    // one float2 wave-store per iter for the first 128 iters (uniform branch).
    float2* enc2 = reinterpret_cast<float2*>(out + OFF_ENC + (size_t)g * 32768 + (size_t)half * 16384);
    const float2 z2 = make_float2(0.f, 0.f);

    const int kbase = half * 256;
    float bd = 3.4e38f;
    int   bk = kbase;

    for (int kk = 0; kk < 256; ++kk) {
        if (kk < 128) enc2[kk * 64 + lane] = z2;   // paced zero-fill

        const int k = kbase + kk;                  // uniform -> emb row via s_load
        const float* __restrict__ e = emb + (size_t)k * 64;
        const float bkk = Bk[k];

        float c0 = 0.f, c1 = 0.f, c2 = 0.f, c3 = 0.f;
        #pragma unroll
        for (int d = 0; d < 64; d += 4) {
            c0 += x[d]     * e[d];
            c1 += x[d + 1] * e[d + 1];
            c2 += x[d + 2] * e[d + 2];
            c3 += x[d + 3] * e[d + 3];
        }
        float dot  = (c0 + c1) + (c2 + c3);
        float dist = (A + bkk) - 2.0f * dot;          // reference op order
        if (dist < bd) { bd = dist; bk = k; }         // strict < = first-min
    }

    sd[wv][lane] = bd;
    sk[wv][lane] = bk;
    __syncthreads();   // drains zero-fill stores (vmcnt(0) before s_barrier) + shares argmins

    // Combine halves for this row (tie -> lower k = half 0).
    const float d0 = sd[gib * 2][lane];
    const float d1 = sd[gib * 2 + 1][lane];
    const int   k0 = sk[gib * 2][lane];
    const int   k1 = sk[gib * 2 + 1][lane];
    const int   kb = (d1 < d0) ? k1 : k0;

    // Counts + one-hot scatter: half-0 wave only (one lane per row of the group).
    if (half == 0) {
        atomicAdd(&counts[kb], 1u);
        out[OFF_ENC + (size_t)g * 32768 + (size_t)lane * 512 + (size_t)kb] = 1.0f;
    }

    // Epilogue: this wave writes channels [half*32, half*32+32) for its row.
    // Compile-time x[] indices in each uniform branch (no scratch).
    const float* __restrict__ eq = emb + (size_t)kb * 64;
    float l0 = 0.f, l1 = 0.f, l2 = 0.f, l3 = 0.f;
    if (half == 0) {
        #pragma unroll
        for (int c = 0; c < 32; c += 4) {
            float q0 = eq[c], q1 = eq[c + 1], q2 = eq[c + 2], q3 = eq[c + 3];
            float e0 = q0 - x[c],     e1 = q1 - x[c + 1];
            float e2 = q2 - x[c + 2], e3 = q3 - x[c + 3];
            l0 += e0 * e0; l1 += e1 * e1; l2 += e2 * e2; l3 += e3 * e3;
            out[OFF_Q + inBase + (size_t)c * 4096]       = x[c]     + e0;
            out[OFF_Q + inBase + (size_t)(c + 1) * 4096] = x[c + 1] + e1;
            out[OFF_Q + inBase + (size_t)(c + 2) * 4096] = x[c + 2] + e2;
            out[OFF_Q + inBase + (size_t)(c + 3) * 4096] = x[c + 3] + e3;
        }
    } else {
        #pragma unroll
        for (int c = 32; c < 64; c += 4) {
            float q0 = eq[c], q1 = eq[c + 1], q2 = eq[c + 2], q3 = eq[c + 3];
            float e0 = q0 - x[c],     e1 = q1 - x[c + 1];
            float e2 = q2 - x[c + 2], e3 = q3 - x[c + 3];
            l0 += e0 * e0; l1 += e1 * e1; l2 += e2 * e2; l3 += e3 * e3;
            out[OFF_Q + inBase + (size_t)c * 4096]       = x[c]     + e0;
            out[OFF_Q + inBase + (size_t)(c + 1) * 4096] = x[c + 1] + e1;
            out[OFF_Q + inBase + (size_t)(c + 2) * 4096] = x[c + 2] + e2;
            out[OFF_Q + inBase + (size_t)(c + 3) * 4096] = x[c + 3] + e3;
        }
    }
    float lsum = (l0 + l1) + (l2 + l3);
    #pragma unroll
    for (int off = 32; off > 0; off >>= 1) lsum += __shfl_down(lsum, off);
    if (lane == 0) {
        unsigned long long fx = (unsigned long long)((double)lsum * 1048576.0);
        atomicAdd(lossAcc, fx);
    }
}

__global__ __launch_bounds__(512) void vq_fin(const unsigned* __restrict__ counts,
                                              const unsigned long long* __restrict__ lossAcc,
                                              float* __restrict__ out) {
    __shared__ float red[512];
    int k = threadIdx.x;
    float p = (float)counts[k] * (1.0f / 131072.0f);  // exact: count * 2^-17
    red[k] = p * logf(p + 1e-10f);
    __syncthreads();
    for (int s = 256; s > 0; s >>= 1) {
        if (k < s) red[k] += red[k + s];
        __syncthreads();
    }
    if (k == 0) {
        out[OFF_PERP] = expf(-red[0]);
        double m = ((double)(*lossAcc) / 1048576.0) / 8388608.0;
        float mf = (float)m;
        out[0] = mf + 0.25f * mf;  // q_latent + 0.25 * e_latent (identical values)
    }
}

extern "C" void kernel_launch(void* const* d_in, const int* in_sizes, int n_in,
                              void* d_out, int out_size, void* d_ws, size_t ws_size,
                              hipStream_t stream) {
    const float* in  = (const float*)d_in[0];
    // d_in[1] = labels (unused by the reference forward)
    const float* emb = (const float*)d_in[2];
    float* out = (float*)d_out;

    float* Bk                    = (float*)d_ws;                              // 512 f32
    unsigned* counts             = (unsigned*)((char*)d_ws + 2048);           // 512 u32
    unsigned long long* lossAcc  = (unsigned long long*)((char*)d_ws + 4096); // 1 u64

    vq_prep<<<1, 512, 0, stream>>>(emb, Bk, counts, lossAcc);
    vq_main<<<1024, 256, 0, stream>>>(in, emb, Bk, counts, lossAcc, out);
    vq_fin<<<1, 512, 0, stream>>>(counts, lossAcc, out);
}